// Round 1
// baseline (257.941 us; speedup 1.0000x reference)
//
#include <hip/hip_runtime.h>
#include <math.h>

typedef int intx4 __attribute__((ext_vector_type(4)));
typedef int intx8 __attribute__((ext_vector_type(8)));
typedef float floatx16 __attribute__((ext_vector_type(16)));

#define N_ROWS 8192
#define KDIM 1024

// E8M0 scale bytes: 123 -> 2^-4 per side (data pre-scaled by 2^4 each side)
#define SCALE_WORD 0x7B7B7B7B

// order-preserving float->int encoding for atomicMax
__device__ __forceinline__ int fenc(float f) {
  int i = __float_as_int(f);
  return i >= 0 ? i : (i ^ 0x7fffffff);
}
__device__ __forceinline__ float fdec(int e) {
  int b = e >= 0 ? e : (e ^ 0x7fffffff);
  return __int_as_float(b);
}

// One WAVE per row (4 rows/block, no __syncthreads): computes 1/||x|| (fp32),
// writes row normalized*16 as e4m3 via HW cvt, inits the max slot.
__global__ __launch_bounds__(256) void normalize_kernel(
    const float* __restrict__ ex, const float* __restrict__ ey,
    unsigned char* __restrict__ exn, unsigned char* __restrict__ eyn,
    int* __restrict__ rowmax, int* __restrict__ colmax) {
  const int wave = threadIdx.x >> 6, lane = threadIdx.x & 63;
  const int gr = blockIdx.x * 4 + wave;  // 0..16383
  const float* x;
  unsigned char* out;
  int* mslot;
  int row;
  if (gr < N_ROWS) {
    x = ex; out = exn; mslot = rowmax; row = gr;
  } else {
    x = ey; out = eyn; mslot = colmax; row = gr - N_ROWS;
  }
  const float4* xr = (const float4*)(x + (size_t)row * KDIM);
  float4 v[4];
  float ss = 0.f;
#pragma unroll
  for (int j = 0; j < 4; ++j) {
    v[j] = xr[lane + j * 64];  // coalesced
    ss += v[j].x * v[j].x + v[j].y * v[j].y + v[j].z * v[j].z + v[j].w * v[j].w;
  }
#pragma unroll
  for (int off = 32; off > 0; off >>= 1) ss += __shfl_xor(ss, off, 64);
  const float rs = 16.0f * rsqrtf(fmaxf(ss, 1e-24f));  // 2^4 pre-scale
  int* op = (int*)(out + (size_t)row * KDIM);
#pragma unroll
  for (int j = 0; j < 4; ++j) {
    int w = __builtin_amdgcn_cvt_pk_fp8_f32(v[j].x * rs, v[j].y * rs, 0, false);
    w = __builtin_amdgcn_cvt_pk_fp8_f32(v[j].z * rs, v[j].w * rs, w, true);
    op[lane + j * 64] = w;
  }
  if (lane == 0) mslot[row] = (int)0x80000000;  // encoded -inf floor
}

// 128x128 tile GEMM (A @ B^T, row-major K-contiguous e4m3) using MX-scaled
// mfma_scale_f32_32x32x64_f8f6f4, fused with row/col max reduction.
//
// Round-12 change: pipe rebalance LDS -> VMEM. Counter math at r11: LDS
// demand ~576 cyc/block-step (48 b128 ops, 52% busy + 11% conflicts) vs
// MFMA 275 (25% = measured MfmaUtil) vs VMEM ~290 (HBM 6%). LDS is the
// binding pipe; VMEM idle. A-tile LDS staging provides only 2-wave reuse
// while each wave already registers its aF once per step -> drop sA
// entirely and read A fragments DIRECT global->reg:
//   lane reads A[bm*128 + wm*64 + mi*32 + l32][k0 + half*32 .. +31]
// as two dwordx4 into the halves of an intx8 union (bitwise-identical
// operand bytes -> absmax stays 0.0). The oLo/oHi pair covers whole 64B
// lines (2 lanes/line); same-bm blocks share an XCD (ids differ by 64),
// so the A panel stays L1/L2-hot. LDS ops/block-step 48 -> 24.
// Union-half loads also replace both shufflevectors (VALU mov reduction).
// Issue order per step: A loads FIRST, then B staging loads -> aF usable
// at vmcnt(2) while B loads stay in flight until post-compute WRITEB.
// LDS 32KB -> 16KB. Regs ~net-zero (pf 16->8, +aF 16): keep (256,4).
// Spill tripwire: WRITE_SIZE (clean ~20 MB; true spill was ~1 GB).
//
// LDS swizzle for B (verified r8): 64-B rows, 16-B chunk c of row r at
// slot c ^ ((r>>1)&3); staging pre-swizzles the global source chunk so
// the linear lane*16 dest lands swizzle-stored; fragment reads recover
// true chunk 2h+j -> operand bytes at (half,j,b) equal global
// k = k0+(2h+j)*16+b -> exact dot-product pairing (absmax 0.0 thru r11).
__global__ __launch_bounds__(256, 4) void gemm_max_kernel(
    const unsigned char* __restrict__ A, const unsigned char* __restrict__ B,
    int* __restrict__ rowmax, int* __restrict__ colmax) {
  constexpr int TM = 128, BK = 64, K = KDIM;
  constexpr int BUF = TM * BK;                          // 8 KB per buffer
  __shared__ __align__(16) unsigned char sB[2 * BUF];   // 16 KB (B only)

  const int bm = blockIdx.x, bn = blockIdx.y;
  const int tid = threadIdx.x;
  const int lane = tid & 63, wave = tid >> 6;
  const int wm = wave >> 1, wn = wave & 1;  // 2x2 waves of 64x64
  const int l32 = lane & 31, half = lane >> 5;
  const int fsw = (l32 >> 1) & 3;                 // f(row) = (row>>1)&3
  const int oLo = (((2 * half + 0) ^ fsw) << 4);  // swizzled slot offsets
  const int oHi = (((2 * half + 1) ^ fsw) << 4);

  const char* Bb = (const char*)(B + (size_t)bn * TM * K);

  // A direct: per-lane base at (row = bm*128 + wm*64 + l32, col = half*32).
  // Per step, mi adds 32 rows, k0 advances 64 bytes.
  const char* gAf =
      (const char*)A + (size_t)(bm * TM + wm * 64 + l32) * K + half * 32;

  typedef union {
    intx8 v8;
    intx4 v4[2];
  } frag8;

  floatx16 acc[2][2] = {};
  frag8 aF[2];

  // B staging: wave w stages rows w*32..+31 per step (2 chunks/lane).
  // Dest (linear lane*16): row r_d = wave*32 + (lane>>2), slot lane&3.
  // Source chunk = (lane&3) ^ f(r_d); +16-row write keeps same offset.
  const int src_c16 = (((lane & 3) ^ ((lane >> 3) & 3)) << 4);
  const char* gB = Bb + (size_t)(wave * 32 + (lane >> 2)) * K + src_c16;
  unsigned char* wB = sB + wave * 2048 + lane * 16;  // linear dest

  intx4 pf[2];  // B prefetch regs (8 VGPRs)

#define LOADA(k0)                                                     \
  do {                                                                \
    aF[0].v4[0] = *(const intx4*)(gAf + (size_t)(k0));                \
    aF[0].v4[1] = *(const intx4*)(gAf + (size_t)(k0) + 16);           \
    aF[1].v4[0] = *(const intx4*)(gAf + (size_t)(k0) + 32 * (size_t)K);      \
    aF[1].v4[1] = *(const intx4*)(gAf + (size_t)(k0) + 32 * (size_t)K + 16); \
  } while (0)

#define LOADB(k0)                                            \
  do {                                                       \
    pf[0] = *(const intx4*)(gB + (size_t)(k0));              \
    pf[1] = *(const intx4*)(gB + (size_t)(k0) + 16 * K);     \
  } while (0)

#define WRITEB(buf)                                          \
  do {                                                       \
    *(intx4*)(wB + (buf)*BUF) = pf[0];                       \
    *(intx4*)(wB + (buf)*BUF + 1024) = pf[1];                \
  } while (0)

#define COMPUTE(cur)                                                        \
  do {                                                                      \
    _Pragma("unroll") for (int ni = 0; ni < 2; ++ni) {                      \
      const unsigned char* bBase =                                          \
          &sB[(cur)*BUF + (wn * 64 + ni * 32 + l32) * BK];                  \
      frag8 bF;                                                             \
      bF.v4[0] = *(const intx4*)(bBase + oLo);                              \
      bF.v4[1] = *(const intx4*)(bBase + oHi);                              \
      _Pragma("unroll") for (int mi = 0; mi < 2; ++mi)                      \
          acc[mi][ni] = __builtin_amdgcn_mfma_scale_f32_32x32x64_f8f6f4(    \
              aF[mi].v8, bF.v8, acc[mi][ni], 0, 0, 0, SCALE_WORD, 0,        \
              SCALE_WORD);                                                  \
    }                                                                       \
  } while (0)

  LOADB(0);
  WRITEB(0);
  __syncthreads();

  // unroll 1: keeps one pf/aF set live (full unroll would hoist -> spill)
#pragma unroll 1
  for (int step = 0; step < K / BK - 1; ++step) {
    LOADA(step * BK);         // aF ready at vmcnt(2)
    LOADB((step + 1) * BK);   // in flight across the whole compute phase
    COMPUTE(step & 1);
    WRITEB((step + 1) & 1);   // vmcnt wait is data-dependent, post-compute
    __syncthreads();
  }
  LOADA((K / BK - 1) * BK);
  COMPUTE((K / BK - 1) & 1);

#undef LOADA
#undef LOADB
#undef WRITEB
#undef COMPUTE

  // 32x32 C/D layout (m74/m101, dtype-independent):
  //   col = lane&31, row = (reg&3) + 8*(reg>>2) + 4*(lane>>5), reg in [0,16)
  // Row maxes: in-lane over ni, shuffle across 32 cols (masks 1..16 stay
  // within a half), l32==0 lanes write.
#pragma unroll
  for (int mi = 0; mi < 2; ++mi) {
#pragma unroll
    for (int reg = 0; reg < 16; ++reg) {
      float v = fmaxf(acc[mi][0][reg], acc[mi][1][reg]);
#pragma unroll
      for (int m = 1; m < 32; m <<= 1) v = fmaxf(v, __shfl_xor(v, m, 64));
      if (l32 == 0) {
        const int grow = bm * TM + wm * 64 + mi * 32 +
                         (reg & 3) + 8 * (reg >> 2) + 4 * half;
        atomicMax(&rowmax[grow], fenc(v));
      }
    }
  }
  // Col maxes: in-lane over mi,reg (32 vals), combine halves via xor 32.
#pragma unroll
  for (int ni = 0; ni < 2; ++ni) {
    float v = -3.402823466e38f;
#pragma unroll
    for (int mi = 0; mi < 2; ++mi)
#pragma unroll
      for (int reg = 0; reg < 16; ++reg) v = fmaxf(v, acc[mi][ni][reg]);
    v = fmaxf(v, __shfl_xor(v, 32, 64));
    if (half == 0) {
      const int gcol = bn * TM + wn * 64 + ni * 32 + l32;
      atomicMax(&colmax[gcol], fenc(v));
    }
  }
}

__global__ __launch_bounds__(1024) void finalize_kernel(
    const int* __restrict__ rowmax, const int* __restrict__ colmax,
    float* __restrict__ out) {
  const int tid = threadIdx.x;
  float s1 = 0.f, s2 = 0.f;
  for (int i = tid; i < N_ROWS; i += 1024) {
    s1 += 1.0f - fdec(rowmax[i]);
    s2 += 1.0f - fdec(colmax[i]);
  }
#pragma unroll
  for (int off = 32; off > 0; off >>= 1) {
    s1 += __shfl_down(s1, off, 64);
    s2 += __shfl_down(s2, off, 64);
  }
  __shared__ float r1[16], r2[16];
  if ((tid & 63) == 0) {
    r1[tid >> 6] = s1;
    r2[tid >> 6] = s2;
  }
  __syncthreads();
  if (tid == 0) {
    const double SIGMA = 0.3;
    const double H_CONST = 0.5 * log(2.0 * 3.14159265358979323846 * SIGMA * SIGMA) + 0.5;
    const float HS = (float)(H_CONST / SIGMA);
    float a1 = 0.f, a2 = 0.f;
#pragma unroll
    for (int w = 0; w < 16; ++w) {
      a1 += r1[w];
      a2 += r2[w];
    }
    out[0] = HS * a1;
    out[1] = HS * a2;
  }
}

extern "C" void kernel_launch(void* const* d_in, const int* in_sizes, int n_in,
                              void* d_out, int out_size, void* d_ws, size_t ws_size,
                              hipStream_t stream) {
  const float* ex = (const float*)d_in[0];
  const float* ey = (const float*)d_in[1];
  float* out = (float*)d_out;
  char* ws = (char*)d_ws;

  unsigned char* exn = (unsigned char*)ws;                                   // 8 MB
  unsigned char* eyn = (unsigned char*)(ws + (size_t)N_ROWS * KDIM);         // 8 MB
  int* rowmax = (int*)(ws + (size_t)N_ROWS * KDIM * 2);                      // 32 KB
  int* colmax = rowmax + N_ROWS;                                             // 32 KB

  normalize_kernel<<<2 * N_ROWS / 4, 256, 0, stream>>>(ex, ey, exn, eyn, rowmax, colmax);
  gemm_max_kernel<<<dim3(64, 64), 256, 0, stream>>>(exn, eyn, rowmax, colmax);
  finalize_kernel<<<1, 1024, 0, stream>>>(rowmax, colmax, out);
}